// Round 10
// baseline (203.443 us; speedup 1.0000x reference)
//
#include <hip/hip_runtime.h>
#include <hip/hip_bf16.h>
#include <cstdint>
#include <cstddef>

typedef __bf16 bf16_t;
typedef __bf16 bf16x8 __attribute__((ext_vector_type(8)));
typedef __bf16 bf16x4 __attribute__((ext_vector_type(4)));
typedef float f32x4 __attribute__((ext_vector_type(4)));
typedef _Float16 f16x8 __attribute__((ext_vector_type(8)));

#define DEVINL __device__ __forceinline__

DEVINL void gload_lds16(const bf16_t* g, bf16_t* l) {
  __builtin_amdgcn_global_load_lds(
      (__attribute__((address_space(1))) void*)(g),
      (__attribute__((address_space(3))) void*)(l), 16, 0, 0);
}

// ---------------------------------------------------------------------------
// cast fp32 -> bf16
// ---------------------------------------------------------------------------
__global__ __launch_bounds__(256) void cast_f32_bf16(
    const float* __restrict__ in, bf16_t* __restrict__ out, long n) {
  long i = ((long)blockIdx.x * 256 + threadIdx.x) * 4;
  if (i + 3 < n) {
    float4 v = *reinterpret_cast<const float4*>(in + i);
    bf16x4 o = { (bf16_t)v.x, (bf16_t)v.y, (bf16_t)v.z, (bf16_t)v.w };
    *reinterpret_cast<bf16x4*>(out + i) = o;
  }
}

// ---------------------------------------------------------------------------
// W [1024][3072] fp32 -> Wt [3072][1024] bf16
// ---------------------------------------------------------------------------
__global__ __launch_bounds__(256) void transpose_W(
    const float* __restrict__ W, bf16_t* __restrict__ Wt) {
  __shared__ bf16_t tile[64][66];
  const int c0 = blockIdx.x * 64, r0 = blockIdx.y * 64;
  const int tc = threadIdx.x & 63, tr = threadIdx.x >> 6;
#pragma unroll
  for (int k = 0; k < 16; ++k) {
    int rl = k * 4 + tr;
    tile[rl][tc] = (bf16_t)W[(size_t)(r0 + rl) * 3072 + c0 + tc];
  }
  __syncthreads();
#pragma unroll
  for (int k = 0; k < 16; ++k) {
    int cl = k * 4 + tr;
    Wt[(size_t)(c0 + cl) * 1024 + r0 + tc] = tile[tc][cl];
  }
}

// ---------------------------------------------------------------------------
// gemm128 (R8 core): C = A[M][K] @ B[N][K]^T. 128x128 tile, 4 waves, BK=32,
// 3 LDS slots, T2 slot-swizzle (conflict-free), vmcnt(4) 2-slot-ahead,
// band rasterization (XCD chunk + GM=8 M-bands).
// EPI 0: Q|K dense bf16 (Q scaled 1/32, +bias); seg 2 writes V TRANSPOSED
//        into VtOut[b][h][n] (bf16x4 over 4 consecutive n).
// EPI 2: fp16 out (S).
// ---------------------------------------------------------------------------
template <int EPI, int NQ>
__global__ __launch_bounds__(256, 2) void gemm128(
    const bf16_t* __restrict__ A, const bf16_t* __restrict__ B,
    void* __restrict__ C, const float* __restrict__ bias,
    int lda, int ldb, int ldc, long sA, long sB, long sC,
    bf16_t* __restrict__ VtOut) {
  __shared__ bf16_t lds[3][256 * 32];  // slot: A 128x32 | B 128x32

  constexpr int GM = 8;
  const int gx = gridDim.x, gy = gridDim.y;
  const int nwg = gx * gy * gridDim.z;
  const int flat = blockIdx.x + gx * (blockIdx.y + gy * blockIdx.z);
  const int v = (flat & 7) * (nwg >> 3) + (flat >> 3);
  const int slice = gx * gy;
  const int bz = v / slice;
  const int rr = v % slice;
  const int BS = GM * gx;
  const int band = rr / BS, tt = rr % BS;
  const int bx = tt / GM;
  const int by = band * GM + (tt % GM);

  const int m0 = by * 128, n0 = bx * 128;
  A += (size_t)bz * sA;
  B += (size_t)bz * sB;

  const int tid = threadIdx.x;
  const int w = tid >> 6, lane = tid & 63;
  const int wr = w >> 1, wc = w & 1;

  const int srow = lane >> 2;
  const int schunk = ((lane & 3) ^ ((lane >> 3) & 3)) * 8;
  const bf16_t* gA = A + (size_t)(m0 + w * 32 + srow) * lda + schunk;
  const bf16_t* gB = B + (size_t)(n0 + w * 32 + srow) * ldb + schunk;

  const int rsel = lane & 15, kg = lane >> 4;
  const int kswz = (kg ^ ((rsel >> 1) & 3)) * 8;
  f32x4 acc[4][4] = {};

#define SA(S, q)                                                              \
  {                                                                           \
    const bf16_t* g = gA + (size_t)(q) * 32;                                  \
    bf16_t* l = &lds[S][(w * 32) * 32];                                       \
    gload_lds16(g, l);                                                        \
    gload_lds16(g + (size_t)16 * lda, l + 16 * 32);                           \
  }
#define SB(S, q)                                                              \
  {                                                                           \
    const bf16_t* g = gB + (size_t)(q) * 32;                                  \
    bf16_t* l = &lds[S][128 * 32 + (w * 32) * 32];                            \
    gload_lds16(g, l);                                                        \
    gload_lds16(g + (size_t)16 * ldb, l + 16 * 32);                           \
  }
#define VMW(N) asm volatile("s_waitcnt vmcnt(%0)" ::"n"(N) : "memory")
#define LKW asm volatile("s_waitcnt lgkmcnt(0)" ::: "memory")
#define BAR __builtin_amdgcn_s_barrier()

  SA(0, 0); SB(0, 0);
  SA(1, 1); SB(1, 1);
  VMW(4);
  BAR;

#pragma unroll
  for (int q = 0; q < NQ; ++q) {
    const int s = q % 3;
    bf16x8 af[4], bfr[4];
#pragma unroll
    for (int j = 0; j < 4; ++j)
      bfr[j] = *reinterpret_cast<const bf16x8*>(
          &lds[s][128 * 32 + (wc * 64 + j * 16 + rsel) * 32 + kswz]);
#pragma unroll
    for (int i = 0; i < 4; ++i)
      af[i] = *reinterpret_cast<const bf16x8*>(
          &lds[s][(wr * 64 + i * 16 + rsel) * 32 + kswz]);
    if (q + 2 < NQ) {
      const int s2 = (q + 2) % 3;
      SA(s2, q + 2);
      SB(s2, q + 2);
    }
    __builtin_amdgcn_s_setprio(1);
#pragma unroll
    for (int i = 0; i < 4; ++i)
#pragma unroll
      for (int j = 0; j < 4; ++j)
        acc[i][j] = __builtin_amdgcn_mfma_f32_16x16x32_bf16(
            af[i], bfr[j], acc[i][j], 0, 0, 0);
    __builtin_amdgcn_s_setprio(0);
    if (q + 1 < NQ) {
      LKW;
      if (q + 2 < NQ) VMW(4); else VMW(0);
      BAR;
    }
  }
#undef SA
#undef SB
#undef VMW
#undef LKW
#undef BAR

  // epilogue: C/D layout col=lane&15, row=(lane>>4)*4+reg (m89-verified)
  const int rb = (lane >> 4) * 4, cs = lane & 15;
  if constexpr (EPI == 0) {
    const int seg = n0 >> 10;
    if (seg < 2) {
      bf16_t* Cb = (bf16_t*)C + (size_t)seg * 8192 * 1024;
      const float scl = (seg == 0) ? 0.03125f : 1.0f;
#pragma unroll
      for (int i = 0; i < 4; ++i)
#pragma unroll
        for (int j = 0; j < 4; ++j)
#pragma unroll
          for (int r = 0; r < 4; ++r) {
            const int row = m0 + wr * 64 + i * 16 + rb + r;
            const int col = n0 + wc * 64 + j * 16 + cs;
            Cb[(size_t)row * 1024 + (col & 1023)] =
                (bf16_t)((acc[i][j][r] + bias[col]) * scl);
          }
    } else {
      // V transposed: Vt[b][h][n], 4 consecutive n per (i,j)
      const int bq = m0 >> 11;
#pragma unroll
      for (int i = 0; i < 4; ++i) {
        const int nloc = (m0 & 2047) + wr * 64 + i * 16 + rb;
#pragma unroll
        for (int j = 0; j < 4; ++j) {
          const int col = n0 + wc * 64 + j * 16 + cs;
          const int h = col & 1023;
          const float bv = bias[col];
          bf16x4 pk;
#pragma unroll
          for (int r = 0; r < 4; ++r) pk[r] = (bf16_t)(acc[i][j][r] + bv);
          *reinterpret_cast<bf16x4*>(
              VtOut + ((size_t)bq * 1024 + h) * 2048 + nloc) = pk;
        }
      }
    }
  } else {
#pragma unroll
    for (int i = 0; i < 4; ++i)
#pragma unroll
      for (int j = 0; j < 4; ++j)
#pragma unroll
        for (int r = 0; r < 4; ++r) {
          const int row = m0 + wr * 64 + i * 16 + rb + r;
          const int col = n0 + wc * 64 + j * 16 + cs;
          ((_Float16*)C)[(size_t)bz * sC + (size_t)row * ldc + col] =
              (_Float16)acc[i][j][r];
        }
  }
}

// ---------------------------------------------------------------------------
// rowstat: per row of S fp16 [8192][2048]: M[row]=max, IV[row]=1/sum(exp)
// ---------------------------------------------------------------------------
__global__ __launch_bounds__(256) void rowstat(
    const _Float16* __restrict__ S, float* __restrict__ Mx,
    float* __restrict__ IV) {
  const long row = blockIdx.x;
  const _Float16* s = S + row * 2048;
  const int tid = threadIdx.x;
  const int wave = tid >> 6, lane = tid & 63;

  float v[8];
  {
    f16x8 hv = *reinterpret_cast<const f16x8*>(s + tid * 8);
#pragma unroll
    for (int k = 0; k < 8; ++k) v[k] = (float)hv[k];
  }
  float m = v[0];
#pragma unroll
  for (int k = 1; k < 8; ++k) m = fmaxf(m, v[k]);
#pragma unroll
  for (int off = 32; off; off >>= 1) m = fmaxf(m, __shfl_xor(m, off));

  __shared__ float red[8];
  if (lane == 0) red[wave] = m;
  __syncthreads();
  m = fmaxf(fmaxf(red[0], red[1]), fmaxf(red[2], red[3]));

  float sum = 0.f;
#pragma unroll
  for (int k = 0; k < 8; ++k) sum += __expf(v[k] - m);
#pragma unroll
  for (int off = 32; off; off >>= 1) sum += __shfl_xor(sum, off);
  if (lane == 0) red[4 + wave] = sum;
  __syncthreads();
  if (tid == 0) {
    sum = red[4] + red[5] + red[6] + red[7];
    Mx[row] = m;
    IV[row] = 1.0f / sum;
  }
}

// ---------------------------------------------------------------------------
// gemm_pv: Out[b][2048][1024] = P @ Vt^T, P = exp(S - m)*inv computed in
// A-staging (reg-stage S fp16 -> transform -> ds_write; T14 issue-early /
// write-late). B (Vt) stays gload_lds. 3 slots, T2 swizzle, band raster.
// vmcnt FIFO (A-pair then B-pair per phase): start VMW(2) pops A_{q+2};
// end VMW(4) pops B_{q+1}. Prologue/tail counts enumerated.
// ---------------------------------------------------------------------------
template <int NQ>
__global__ __launch_bounds__(256, 2) void gemm_pv(
    const _Float16* __restrict__ S, const bf16_t* __restrict__ Vt,
    float* __restrict__ Out, const float* __restrict__ Mx,
    const float* __restrict__ IV) {
  __shared__ bf16_t lds[3][256 * 32];

  constexpr int GM = 8;
  const int gx = gridDim.x, gy = gridDim.y;
  const int nwg = gx * gy * gridDim.z;
  const int flat = blockIdx.x + gx * (blockIdx.y + gy * blockIdx.z);
  const int v = (flat & 7) * (nwg >> 3) + (flat >> 3);
  const int slice = gx * gy;
  const int bz = v / slice;
  const int rr = v % slice;
  const int BS = GM * gx;
  const int band = rr / BS, tt = rr % BS;
  const int bx = tt / GM;
  const int by = band * GM + (tt % GM);
  const int m0 = by * 128, n0 = bx * 128;

  const _Float16* Sb = S + (size_t)bz * 2048 * 2048;
  const bf16_t* Vb = Vt + (size_t)bz * 1024 * 2048;

  const int tid = threadIdx.x;
  const int w = tid >> 6, lane = tid & 63;
  const int wr = w >> 1, wc = w & 1;
  const int srow = lane >> 2;
  const int schunk = ((lane & 3) ^ ((lane >> 3) & 3)) * 8;
  const _Float16* gA = Sb + (size_t)(m0 + w * 32 + srow) * 2048 + schunk;
  const bf16_t* gB = Vb + (size_t)(n0 + w * 32 + srow) * 2048 + schunk;

  const int ridx = bz * 2048 + m0 + w * 32 + srow;
  const float ms0 = Mx[ridx], iv0 = IV[ridx];
  const float ms1 = Mx[ridx + 16], iv1 = IV[ridx + 16];

  const int rsel = lane & 15, kg = lane >> 4;
  const int kswz = (kg ^ ((rsel >> 1) & 3)) * 8;
  f32x4 acc[4][4] = {};
  f16x8 u0, u1, w0, w1;  // reg sets: U = even tiles, W = odd tiles

#define LD_U(q)                                                               \
  {                                                                           \
    u0 = *reinterpret_cast<const f16x8*>(gA + (size_t)(q) * 32);              \
    u1 = *reinterpret_cast<const f16x8*>(gA + (size_t)(q) * 32 + 16 * 2048);  \
  }
#define LD_W(q)                                                               \
  {                                                                           \
    w0 = *reinterpret_cast<const f16x8*>(gA + (size_t)(q) * 32);              \
    w1 = *reinterpret_cast<const f16x8*>(gA + (size_t)(q) * 32 + 16 * 2048);  \
  }
#define DSW(SLOT, A0, A1)                                                     \
  {                                                                           \
    bf16x8 o0, o1;                                                            \
    _Pragma("unroll") for (int k2 = 0; k2 < 8; ++k2) {                        \
      o0[k2] = (bf16_t)(__expf((float)A0[k2] - ms0) * iv0);                   \
      o1[k2] = (bf16_t)(__expf((float)A1[k2] - ms1) * iv1);                   \
    }                                                                         \
    bf16_t* l = &lds[SLOT][(w * 32) * 32];                                    \
    *reinterpret_cast<bf16x8*>(l + lane * 8) = o0;                            \
    *reinterpret_cast<bf16x8*>(l + 16 * 32 + lane * 8) = o1;                  \
  }
#define SBGL(SLOT, q)                                                         \
  {                                                                           \
    const bf16_t* g = gB + (size_t)(q) * 32;                                  \
    bf16_t* l = &lds[SLOT][128 * 32 + (w * 32) * 32];                         \
    gload_lds16(g, l);                                                        \
    gload_lds16(g + (size_t)16 * 2048, l + 16 * 32);                          \
  }
#define VMW(N) asm volatile("s_waitcnt vmcnt(%0)" ::"n"(N) : "memory")
#define LKW asm volatile("s_waitcnt lgkmcnt(0)" ::: "memory")
#define BAR __builtin_amdgcn_s_barrier()
#define SCB __builtin_amdgcn_sched_barrier(0)

  // prologue: A0->U, A1->W, B0, B1; write slots 0,1; preload A2->U
  LD_U(0);
  LD_W(1);
  SCB;
  SBGL(0, 0);
  SBGL(1, 1);
  VMW(2);  // A0,A1 landed (B0,B1 outstanding)
  DSW(0, u0, u1);
  DSW(1, w0, w1);
  LD_U(2);
  SCB;
  VMW(2);  // B0,B1 landed (A2 outstanding)
  LKW;
  BAR;

#pragma unroll
  for (int q = 0; q < NQ; ++q) {
    const int s = q % 3, s2 = (q + 2) % 3;
    if (q == 0) { VMW(0); }           // A2 landed
    else if (q <= NQ - 3) { VMW(2); } // A_{q+2} landed
    if (q <= NQ - 3) {
      if (q & 1) { DSW(s2, w0, w1); } else { DSW(s2, u0, u1); }
    }
    bf16x8 af[4], bfr[4];
#pragma unroll
    for (int j = 0; j < 4; ++j)
      bfr[j] = *reinterpret_cast<const bf16x8*>(
          &lds[s][128 * 32 + (wc * 64 + j * 16 + rsel) * 32 + kswz]);
#pragma unroll
    for (int i = 0; i < 4; ++i)
      af[i] = *reinterpret_cast<const bf16x8*>(
          &lds[s][(wr * 64 + i * 16 + rsel) * 32 + kswz]);
    if (q <= NQ - 4) {
      if (q & 1) { LD_U(q + 3); } else { LD_W(q + 3); }
    }
    SCB;  // pin A-loads before B gloads (vmcnt FIFO order)
    if (q <= NQ - 3) SBGL(s2, q + 2);
    __builtin_amdgcn_s_setprio(1);
#pragma unroll
    for (int i = 0; i < 4; ++i)
#pragma unroll
      for (int j = 0; j < 4; ++j)
        acc[i][j] = __builtin_amdgcn_mfma_f32_16x16x32_bf16(
            af[i], bfr[j], acc[i][j], 0, 0, 0);
    __builtin_amdgcn_s_setprio(0);
    if (q < NQ - 1) {
      LKW;
      if (q <= NQ - 4) { VMW(4); }       // B_{q+1} landed
      else if (q == NQ - 3) { VMW(2); }  // B_{NQ-2} landed
      else { VMW(0); }                   // q == NQ-2: B_{NQ-1} landed
      BAR;
    }
  }
#undef LD_U
#undef LD_W
#undef DSW
#undef SBGL
#undef VMW
#undef LKW
#undef BAR
#undef SCB

  // epilogue: fp32 out
  const int rb = (lane >> 4) * 4, cs = lane & 15;
  float* Ob = Out + (size_t)bz * 2048 * 1024;
#pragma unroll
  for (int i = 0; i < 4; ++i)
#pragma unroll
    for (int j = 0; j < 4; ++j)
#pragma unroll
      for (int r = 0; r < 4; ++r) {
        const int row = m0 + wr * 64 + i * 16 + rb + r;
        const int col = n0 + wc * 64 + j * 16 + cs;
        Ob[(size_t)row * 1024 + col] = acc[i][j][r];
      }
}

// ---------------------------------------------------------------------------
// launch
// ---------------------------------------------------------------------------
extern "C" void kernel_launch(void* const* d_in, const int* in_sizes, int n_in,
                              void* d_out, int out_size, void* d_ws,
                              size_t ws_size, hipStream_t stream) {
  const float* x = (const float*)d_in[0];  // [4,2048,1024]
  const float* W = (const float*)d_in[1];  // [1024,3072]
  const float* b = (const float*)d_in[2];  // [3072]
  float* out = (float*)d_out;              // [4,2048,1024] fp32

  char* w = (char*)d_ws;
  bf16_t* xb = (bf16_t*)w;    w += (size_t)8192 * 1024 * 2;
  bf16_t* Wt = (bf16_t*)w;    w += (size_t)3072 * 1024 * 2;
  bf16_t* QKV = (bf16_t*)w;   w += (size_t)2 * 8192 * 1024 * 2;  // Q,K dense
  bf16_t* Vt = (bf16_t*)w;    w += (size_t)4 * 1024 * 2048 * 2;
  _Float16* S = (_Float16*)w; w += (size_t)4 * 2048 * 2048 * 2;
  float* M = (float*)w;       w += (size_t)8192 * 4;
  float* IV = (float*)w;      w += (size_t)8192 * 4;

  bf16_t* Q = QKV;
  bf16_t* Kd = QKV + (size_t)8192 * 1024;

  cast_f32_bf16<<<8192, 256, 0, stream>>>(x, xb, (long)8192 * 1024);
  transpose_W<<<dim3(48, 16), 256, 0, stream>>>(W, Wt);

  // Q|K dense + V transposed into Vt. grid 24x64 = 1536 blocks
  gemm128<0, 32><<<dim3(24, 64, 1), 256, 0, stream>>>(
      xb, Wt, QKV, b, 1024, 1024, 1024, 0, 0, 0, Vt);

  // S = Qs @ K^T, fp16 out. grid 16x16x4 = 1024 blocks
  gemm128<2, 32><<<dim3(16, 16, 4), 256, 0, stream>>>(
      Q, Kd, S, nullptr, 1024, 1024, 2048,
      (long)2048 * 1024, (long)2048 * 1024, (long)2048 * 2048, nullptr);

  // per-row max + 1/sum(exp)
  rowstat<<<8192, 256, 0, stream>>>(S, M, IV);

  // out = softmax(S) @ Vt^T (softmax fused into A-staging)
  gemm_pv<64><<<dim3(8, 16, 4), 256, 0, stream>>>(S, Vt, out, M, IV);
}

// Round 11
// 166.380 us; speedup vs baseline: 1.2228x; 1.2228x over previous
//
#include <hip/hip_runtime.h>
#include <hip/hip_bf16.h>
#include <cstdint>
#include <cstddef>

typedef __bf16 bf16_t;
typedef __bf16 bf16x8 __attribute__((ext_vector_type(8)));
typedef __bf16 bf16x4 __attribute__((ext_vector_type(4)));
typedef float f32x4 __attribute__((ext_vector_type(4)));

#define DEVINL __device__ __forceinline__

DEVINL void gload_lds16(const bf16_t* g, bf16_t* l) {
  __builtin_amdgcn_global_load_lds(
      (__attribute__((address_space(1))) void*)(g),
      (__attribute__((address_space(3))) void*)(l), 16, 0, 0);
}

// ---------------------------------------------------------------------------
// zero fp32 buffer (Rsum accumulators; ws is poisoned, so zero every call)
// ---------------------------------------------------------------------------
__global__ __launch_bounds__(256) void zero_f32(float* __restrict__ p, int n) {
  int i = blockIdx.x * 256 + threadIdx.x;
  if (i < n) p[i] = 0.f;
}

// ---------------------------------------------------------------------------
// cast fp32 -> bf16
// ---------------------------------------------------------------------------
__global__ __launch_bounds__(256) void cast_f32_bf16(
    const float* __restrict__ in, bf16_t* __restrict__ out, long n) {
  long i = ((long)blockIdx.x * 256 + threadIdx.x) * 4;
  if (i + 3 < n) {
    float4 v = *reinterpret_cast<const float4*>(in + i);
    bf16x4 o = { (bf16_t)v.x, (bf16_t)v.y, (bf16_t)v.z, (bf16_t)v.w };
    *reinterpret_cast<bf16x4*>(out + i) = o;
  }
}

// ---------------------------------------------------------------------------
// W [1024][3072] fp32 -> Wt [3072][1024] bf16
// ---------------------------------------------------------------------------
__global__ __launch_bounds__(256) void transpose_W(
    const float* __restrict__ W, bf16_t* __restrict__ Wt) {
  __shared__ bf16_t tile[64][66];
  const int c0 = blockIdx.x * 64, r0 = blockIdx.y * 64;
  const int tc = threadIdx.x & 63, tr = threadIdx.x >> 6;
#pragma unroll
  for (int k = 0; k < 16; ++k) {
    int rl = k * 4 + tr;
    tile[rl][tc] = (bf16_t)W[(size_t)(r0 + rl) * 3072 + c0 + tc];
  }
  __syncthreads();
#pragma unroll
  for (int k = 0; k < 16; ++k) {
    int cl = k * 4 + tr;
    Wt[(size_t)(c0 + cl) * 1024 + r0 + tc] = tile[tc][cl];
  }
}

// ---------------------------------------------------------------------------
// gemm128 (R8 core, unchanged): C = A[M][K] @ B[N][K]^T. 128x128 tile,
// 4 waves, BK=32, 3 LDS slots, T2 slot-swizzle (conflict-free, verified 0),
// vmcnt(4) 2-slot-ahead, band rasterization (XCD chunk + GM=8 M-bands).
// EPI 0: Q|K dense bf16 (Q scaled 1/32, +bias); seg 2 writes V TRANSPOSED
//        into VtOut[b][h][n] (bf16x4 over 4 consecutive n).
// EPI 2: E = exp(acc) bf16 out (max-free softmax numerator; |S|<=32 so
//        overflow-impossible) + per-row partial sums -> atomicAdd Rsum.
// EPI 1: fp32 out scaled by 1/Rsum[row]  (softmax denominator folded here).
// ---------------------------------------------------------------------------
template <int EPI, int NQ>
__global__ __launch_bounds__(256, 2) void gemm128(
    const bf16_t* __restrict__ A, const bf16_t* __restrict__ B,
    void* __restrict__ C, const float* __restrict__ bias,
    int lda, int ldb, int ldc, long sA, long sB, long sC,
    bf16_t* __restrict__ VtOut, float* __restrict__ Rsum) {
  __shared__ bf16_t lds[3][256 * 32];  // slot: A 128x32 | B 128x32

  constexpr int GM = 8;
  const int gx = gridDim.x, gy = gridDim.y;
  const int nwg = gx * gy * gridDim.z;
  const int flat = blockIdx.x + gx * (blockIdx.y + gy * blockIdx.z);
  const int v = (flat & 7) * (nwg >> 3) + (flat >> 3);
  const int slice = gx * gy;
  const int bz = v / slice;
  const int rr = v % slice;
  const int BS = GM * gx;
  const int band = rr / BS, tt = rr % BS;
  const int bx = tt / GM;
  const int by = band * GM + (tt % GM);

  const int m0 = by * 128, n0 = bx * 128;
  A += (size_t)bz * sA;
  B += (size_t)bz * sB;

  const int tid = threadIdx.x;
  const int w = tid >> 6, lane = tid & 63;
  const int wr = w >> 1, wc = w & 1;

  const int srow = lane >> 2;
  const int schunk = ((lane & 3) ^ ((lane >> 3) & 3)) * 8;
  const bf16_t* gA = A + (size_t)(m0 + w * 32 + srow) * lda + schunk;
  const bf16_t* gB = B + (size_t)(n0 + w * 32 + srow) * ldb + schunk;

  const int rsel = lane & 15, kg = lane >> 4;
  const int kswz = (kg ^ ((rsel >> 1) & 3)) * 8;
  f32x4 acc[4][4] = {};

#define SA(S, q)                                                              \
  {                                                                           \
    const bf16_t* g = gA + (size_t)(q) * 32;                                  \
    bf16_t* l = &lds[S][(w * 32) * 32];                                       \
    gload_lds16(g, l);                                                        \
    gload_lds16(g + (size_t)16 * lda, l + 16 * 32);                           \
  }
#define SB(S, q)                                                              \
  {                                                                           \
    const bf16_t* g = gB + (size_t)(q) * 32;                                  \
    bf16_t* l = &lds[S][128 * 32 + (w * 32) * 32];                            \
    gload_lds16(g, l);                                                        \
    gload_lds16(g + (size_t)16 * ldb, l + 16 * 32);                           \
  }
#define VMW(N) asm volatile("s_waitcnt vmcnt(%0)" ::"n"(N) : "memory")
#define LKW asm volatile("s_waitcnt lgkmcnt(0)" ::: "memory")
#define BAR __builtin_amdgcn_s_barrier()

  SA(0, 0); SB(0, 0);
  SA(1, 1); SB(1, 1);
  VMW(4);
  BAR;

#pragma unroll
  for (int q = 0; q < NQ; ++q) {
    const int s = q % 3;
    bf16x8 af[4], bfr[4];
#pragma unroll
    for (int j = 0; j < 4; ++j)
      bfr[j] = *reinterpret_cast<const bf16x8*>(
          &lds[s][128 * 32 + (wc * 64 + j * 16 + rsel) * 32 + kswz]);
#pragma unroll
    for (int i = 0; i < 4; ++i)
      af[i] = *reinterpret_cast<const bf16x8*>(
          &lds[s][(wr * 64 + i * 16 + rsel) * 32 + kswz]);
    if (q + 2 < NQ) {
      const int s2 = (q + 2) % 3;
      SA(s2, q + 2);
      SB(s2, q + 2);
    }
    __builtin_amdgcn_s_setprio(1);
#pragma unroll
    for (int i = 0; i < 4; ++i)
#pragma unroll
      for (int j = 0; j < 4; ++j)
        acc[i][j] = __builtin_amdgcn_mfma_f32_16x16x32_bf16(
            af[i], bfr[j], acc[i][j], 0, 0, 0);
    __builtin_amdgcn_s_setprio(0);
    if (q + 1 < NQ) {
      LKW;
      if (q + 2 < NQ) VMW(4); else VMW(0);
      BAR;
    }
  }
#undef SA
#undef SB
#undef VMW
#undef LKW
#undef BAR

  // epilogue: C/D layout col=lane&15, row=(lane>>4)*4+reg (m89-verified)
  const int rb = (lane >> 4) * 4, cs = lane & 15;
  if constexpr (EPI == 0) {
    const int seg = n0 >> 10;
    if (seg < 2) {
      bf16_t* Cb = (bf16_t*)C + (size_t)seg * 8192 * 1024;
      const float scl = (seg == 0) ? 0.03125f : 1.0f;
#pragma unroll
      for (int i = 0; i < 4; ++i)
#pragma unroll
        for (int j = 0; j < 4; ++j)
#pragma unroll
          for (int r = 0; r < 4; ++r) {
            const int row = m0 + wr * 64 + i * 16 + rb + r;
            const int col = n0 + wc * 64 + j * 16 + cs;
            Cb[(size_t)row * 1024 + (col & 1023)] =
                (bf16_t)((acc[i][j][r] + bias[col]) * scl);
          }
    } else {
      // V transposed: Vt[b][h][n], 4 consecutive n per (i,j)
      const int bq = m0 >> 11;
#pragma unroll
      for (int i = 0; i < 4; ++i) {
        const int nloc = (m0 & 2047) + wr * 64 + i * 16 + rb;
#pragma unroll
        for (int j = 0; j < 4; ++j) {
          const int col = n0 + wc * 64 + j * 16 + cs;
          const int h = col & 1023;
          const float bv = bias[col];
          bf16x4 pk;
#pragma unroll
          for (int r = 0; r < 4; ++r) pk[r] = (bf16_t)(acc[i][j][r] + bv);
          *reinterpret_cast<bf16x4*>(
              VtOut + ((size_t)bq * 1024 + h) * 2048 + nloc) = pk;
        }
      }
    }
  } else if constexpr (EPI == 2) {
    // E = exp(acc) bf16 + per-row partial sums -> Rsum (device atomics)
    bf16_t* Cb = (bf16_t*)C;
    float rsum[4][4];  // [i][r]
#pragma unroll
    for (int i = 0; i < 4; ++i)
#pragma unroll
      for (int r = 0; r < 4; ++r) rsum[i][r] = 0.f;
#pragma unroll
    for (int i = 0; i < 4; ++i)
#pragma unroll
      for (int j = 0; j < 4; ++j)
#pragma unroll
        for (int r = 0; r < 4; ++r) {
          const int row = m0 + wr * 64 + i * 16 + rb + r;
          const int col = n0 + wc * 64 + j * 16 + cs;
          const float e = __expf(acc[i][j][r]);
          Cb[(size_t)bz * sC + (size_t)row * ldc + col] = (bf16_t)e;
          rsum[i][r] += e;
        }
    // reduce over the 16-lane column group (cs), then one atomic per row
#pragma unroll
    for (int off = 1; off < 16; off <<= 1)
#pragma unroll
      for (int i = 0; i < 4; ++i)
#pragma unroll
        for (int r = 0; r < 4; ++r)
          rsum[i][r] += __shfl_xor(rsum[i][r], off);
    if ((lane & 15) == 0) {
#pragma unroll
      for (int i = 0; i < 4; ++i)
#pragma unroll
        for (int r = 0; r < 4; ++r)
          atomicAdd(&Rsum[bz * 2048 + m0 + wr * 64 + i * 16 + rb + r],
                    rsum[i][r]);
    }
  } else {
    // fp32 out, normalized by 1/Rsum[row]
    float* Ob = (float*)C + (size_t)bz * sC;
#pragma unroll
    for (int i = 0; i < 4; ++i) {
#pragma unroll
      for (int r = 0; r < 4; ++r) {
        const int row = m0 + wr * 64 + i * 16 + rb + r;
        const float inv = 1.0f / Rsum[bz * 2048 + row];
#pragma unroll
        for (int j = 0; j < 4; ++j) {
          const int col = n0 + wc * 64 + j * 16 + cs;
          Ob[(size_t)row * ldc + col] = acc[i][j][r] * inv;
        }
      }
    }
  }
}

// ---------------------------------------------------------------------------
// launch
// ---------------------------------------------------------------------------
extern "C" void kernel_launch(void* const* d_in, const int* in_sizes, int n_in,
                              void* d_out, int out_size, void* d_ws,
                              size_t ws_size, hipStream_t stream) {
  const float* x = (const float*)d_in[0];  // [4,2048,1024]
  const float* W = (const float*)d_in[1];  // [1024,3072]
  const float* b = (const float*)d_in[2];  // [3072]
  float* out = (float*)d_out;              // [4,2048,1024] fp32

  char* w = (char*)d_ws;
  bf16_t* xb = (bf16_t*)w;   w += (size_t)8192 * 1024 * 2;
  bf16_t* Wt = (bf16_t*)w;   w += (size_t)3072 * 1024 * 2;
  bf16_t* QKV = (bf16_t*)w;  w += (size_t)2 * 8192 * 1024 * 2;  // Q,K dense
  bf16_t* Vt = (bf16_t*)w;   w += (size_t)4 * 1024 * 2048 * 2;
  bf16_t* E = (bf16_t*)w;    w += (size_t)4 * 2048 * 2048 * 2;  // exp(S)
  float* Rsum = (float*)w;   w += (size_t)8192 * 4;

  bf16_t* Q = QKV;
  bf16_t* Kd = QKV + (size_t)8192 * 1024;

  zero_f32<<<32, 256, 0, stream>>>(Rsum, 8192);
  cast_f32_bf16<<<8192, 256, 0, stream>>>(x, xb, (long)8192 * 1024);
  transpose_W<<<dim3(48, 16), 256, 0, stream>>>(W, Wt);

  // Q|K dense + V transposed into Vt. grid 24x64 = 1536 blocks
  gemm128<0, 32><<<dim3(24, 64, 1), 256, 0, stream>>>(
      xb, Wt, QKV, b, 1024, 1024, 1024, 0, 0, 0, Vt, nullptr);

  // E = exp(Qs @ K^T) bf16 + row sums. grid 16x16x4 = 1024 blocks
  gemm128<2, 32><<<dim3(16, 16, 4), 256, 0, stream>>>(
      Q, Kd, E, nullptr, 1024, 1024, 2048,
      (long)2048 * 1024, (long)2048 * 1024, (long)2048 * 2048,
      nullptr, Rsum);

  // out = (E @ Vt^T) / Rsum[row], fp32. grid 8x16x4 = 512 blocks
  gemm128<1, 64><<<dim3(8, 16, 4), 256, 0, stream>>>(
      E, Vt, out, nullptr, 2048, 2048, 1024,
      (long)2048 * 2048, (long)1024 * 2048, (long)2048 * 1024,
      nullptr, Rsum);
}

// Round 12
// 153.625 us; speedup vs baseline: 1.3243x; 1.0830x over previous
//
#include <hip/hip_runtime.h>
#include <hip/hip_bf16.h>
#include <cstdint>
#include <cstddef>

typedef __bf16 bf16_t;
typedef __bf16 bf16x8 __attribute__((ext_vector_type(8)));
typedef __bf16 bf16x4 __attribute__((ext_vector_type(4)));
typedef float f32x4 __attribute__((ext_vector_type(4)));

#define DEVINL __device__ __forceinline__

DEVINL void gload_lds16(const bf16_t* g, bf16_t* l) {
  __builtin_amdgcn_global_load_lds(
      (__attribute__((address_space(1))) void*)(g),
      (__attribute__((address_space(3))) void*)(l), 16, 0, 0);
}

// ---------------------------------------------------------------------------
// zero fp32 buffer (Rsum accumulators; ws is poisoned, so zero every call)
// ---------------------------------------------------------------------------
__global__ __launch_bounds__(256) void zero_f32(float* __restrict__ p, int n) {
  int i = blockIdx.x * 256 + threadIdx.x;
  if (i < n) p[i] = 0.f;
}

// ---------------------------------------------------------------------------
// cast fp32 -> bf16
// ---------------------------------------------------------------------------
__global__ __launch_bounds__(256) void cast_f32_bf16(
    const float* __restrict__ in, bf16_t* __restrict__ out, long n) {
  long i = ((long)blockIdx.x * 256 + threadIdx.x) * 4;
  if (i + 3 < n) {
    float4 v = *reinterpret_cast<const float4*>(in + i);
    bf16x4 o = { (bf16_t)v.x, (bf16_t)v.y, (bf16_t)v.z, (bf16_t)v.w };
    *reinterpret_cast<bf16x4*>(out + i) = o;
  }
}

// ---------------------------------------------------------------------------
// W [1024][3072] fp32 -> Wt [3072][1024] bf16
// ---------------------------------------------------------------------------
__global__ __launch_bounds__(256) void transpose_W(
    const float* __restrict__ W, bf16_t* __restrict__ Wt) {
  __shared__ bf16_t tile[64][66];
  const int c0 = blockIdx.x * 64, r0 = blockIdx.y * 64;
  const int tc = threadIdx.x & 63, tr = threadIdx.x >> 6;
#pragma unroll
  for (int k = 0; k < 16; ++k) {
    int rl = k * 4 + tr;
    tile[rl][tc] = (bf16_t)W[(size_t)(r0 + rl) * 3072 + c0 + tc];
  }
  __syncthreads();
#pragma unroll
  for (int k = 0; k < 16; ++k) {
    int cl = k * 4 + tr;
    Wt[(size_t)(c0 + cl) * 1024 + r0 + tc] = tile[tc][cl];
  }
}

// ---------------------------------------------------------------------------
// gemm128 BK=64: C = A[M][K] @ B[N][K]^T. 128x128 tile, 4 waves, BK=64
// (HALVES phase-slot count — R11 model: time ≈ slots x fixed tax), 2 LDS
// slots (64 KB -> 2 blocks/CU), 1-ahead staging, phase-end vmcnt(0)
// (phase ~1300cyc > ~900cyc HBM latency -> no stall).
// Swizzle (128B rows): phys 16B-slot = (ks*4+kg) ^ (row&7); staging source
// chunk = (lane&7)^(lane>>3) (8-row stripes; round-trip verified).
// EPI 0: Q|K dense bf16 (Q scaled 1/32, +bias); seg 2 writes V transposed.
// EPI 2: E = exp(acc) bf16 + per-row sums -> atomicAdd Rsum (max-free).
// EPI 1: fp32 out scaled by 1/Rsum[row].
// ---------------------------------------------------------------------------
template <int EPI, int NQ>
__global__ __launch_bounds__(256, 2) void gemm128(
    const bf16_t* __restrict__ A, const bf16_t* __restrict__ B,
    void* __restrict__ C, const float* __restrict__ bias,
    int lda, int ldb, int ldc, long sA, long sB, long sC,
    bf16_t* __restrict__ VtOut, float* __restrict__ Rsum) {
  __shared__ bf16_t lds[2][256 * 64];  // slot: A 128x64 | B 128x64

  constexpr int GM = 8;
  const int gx = gridDim.x, gy = gridDim.y;
  const int nwg = gx * gy * gridDim.z;
  const int flat = blockIdx.x + gx * (blockIdx.y + gy * blockIdx.z);
  const int v = (flat & 7) * (nwg >> 3) + (flat >> 3);
  const int slice = gx * gy;
  const int bz = v / slice;
  const int rr = v % slice;
  const int BS = GM * gx;
  const int band = rr / BS, tt = rr % BS;
  const int bx = tt / GM;
  const int by = band * GM + (tt % GM);

  const int m0 = by * 128, n0 = bx * 128;
  A += (size_t)bz * sA;
  B += (size_t)bz * sB;

  const int tid = threadIdx.x;
  const int w = tid >> 6, lane = tid & 63;
  const int wr = w >> 1, wc = w & 1;

  // staging: 8-row stripes; lane -> row = lane>>3, chunk = (lane&7)^(lane>>3)
  const int srow = lane >> 3;
  const int schunk = ((lane & 7) ^ (lane >> 3)) * 8;
  const bf16_t* gA = A + (size_t)(m0 + w * 32 + srow) * lda + schunk;
  const bf16_t* gB = B + (size_t)(n0 + w * 32 + srow) * ldb + schunk;

  const int rsel = lane & 15, kg = lane >> 4;
  // read-side phys-slot offsets (elements): ((ks*4+kg)^(rsel&7))*8
  const int ksw0 = ((kg) ^ (rsel & 7)) * 8;
  const int ksw1 = ((4 + kg) ^ (rsel & 7)) * 8;
  f32x4 acc[4][4] = {};

#define SA(S, q)                                                              \
  _Pragma("unroll") for (int p = 0; p < 4; ++p)                               \
      gload_lds16(gA + (size_t)(q) * 64 + (size_t)(p * 8) * lda,              \
                  &lds[S][(w * 32 + p * 8) * 64]);
#define SB(S, q)                                                              \
  _Pragma("unroll") for (int p = 0; p < 4; ++p)                               \
      gload_lds16(gB + (size_t)(q) * 64 + (size_t)(p * 8) * ldb,              \
                  &lds[S][128 * 64 + (w * 32 + p * 8) * 64]);
#define VMW(N) asm volatile("s_waitcnt vmcnt(%0)" ::"n"(N) : "memory")
#define LKW asm volatile("s_waitcnt lgkmcnt(0)" ::: "memory")
#define BAR __builtin_amdgcn_s_barrier()

  SA(0, 0); SB(0, 0);
  VMW(0);
  BAR;

#pragma unroll
  for (int q = 0; q < NQ; ++q) {
    const int s = q & 1;
    if (q + 1 < NQ) {
      SA(s ^ 1, q + 1);
      SB(s ^ 1, q + 1);
    }
    bf16x8 af[4][2], bfr[4][2];
#pragma unroll
    for (int j = 0; j < 4; ++j) {
      const int rowb = 128 * 64 + (wc * 64 + j * 16 + rsel) * 64;
      bfr[j][0] = *reinterpret_cast<const bf16x8*>(&lds[s][rowb + ksw0]);
      bfr[j][1] = *reinterpret_cast<const bf16x8*>(&lds[s][rowb + ksw1]);
    }
#pragma unroll
    for (int i = 0; i < 4; ++i) {
      const int rowa = (wr * 64 + i * 16 + rsel) * 64;
      af[i][0] = *reinterpret_cast<const bf16x8*>(&lds[s][rowa + ksw0]);
      af[i][1] = *reinterpret_cast<const bf16x8*>(&lds[s][rowa + ksw1]);
    }
    __builtin_amdgcn_s_setprio(1);
#pragma unroll
    for (int ks = 0; ks < 2; ++ks)
#pragma unroll
      for (int i = 0; i < 4; ++i)
#pragma unroll
        for (int j = 0; j < 4; ++j)
          acc[i][j] = __builtin_amdgcn_mfma_f32_16x16x32_bf16(
              af[i][ks], bfr[j][ks], acc[i][j], 0, 0, 0);
    __builtin_amdgcn_s_setprio(0);
    if (q + 1 < NQ) {
      LKW;   // slot-s frag reads retired (WAR vs next phase's staging)
      VMW(0);  // tile q+1 landed -> visible to all after BAR
      BAR;
    }
  }
#undef SA
#undef SB
#undef VMW
#undef LKW
#undef BAR

  // epilogue: C/D layout col=lane&15, row=(lane>>4)*4+reg (m89-verified)
  const int rb = (lane >> 4) * 4, cs = lane & 15;
  if constexpr (EPI == 0) {
    const int seg = n0 >> 10;
    if (seg < 2) {
      bf16_t* Cb = (bf16_t*)C + (size_t)seg * 8192 * 1024;
      const float scl = (seg == 0) ? 0.03125f : 1.0f;
#pragma unroll
      for (int i = 0; i < 4; ++i)
#pragma unroll
        for (int j = 0; j < 4; ++j)
#pragma unroll
          for (int r = 0; r < 4; ++r) {
            const int row = m0 + wr * 64 + i * 16 + rb + r;
            const int col = n0 + wc * 64 + j * 16 + cs;
            Cb[(size_t)row * 1024 + (col & 1023)] =
                (bf16_t)((acc[i][j][r] + bias[col]) * scl);
          }
    } else {
      // V transposed: Vt[b][h][n], 4 consecutive n per (i,j)
      const int bq = m0 >> 11;
#pragma unroll
      for (int i = 0; i < 4; ++i) {
        const int nloc = (m0 & 2047) + wr * 64 + i * 16 + rb;
#pragma unroll
        for (int j = 0; j < 4; ++j) {
          const int col = n0 + wc * 64 + j * 16 + cs;
          const int h = col & 1023;
          const float bv = bias[col];
          bf16x4 pk;
#pragma unroll
          for (int r = 0; r < 4; ++r) pk[r] = (bf16_t)(acc[i][j][r] + bv);
          *reinterpret_cast<bf16x4*>(
              VtOut + ((size_t)bq * 1024 + h) * 2048 + nloc) = pk;
        }
      }
    }
  } else if constexpr (EPI == 2) {
    // E = exp(acc) bf16 + per-row partial sums -> Rsum (device atomics)
    bf16_t* Cb = (bf16_t*)C;
    float rsum[4][4];  // [i][r]
#pragma unroll
    for (int i = 0; i < 4; ++i)
#pragma unroll
      for (int r = 0; r < 4; ++r) rsum[i][r] = 0.f;
#pragma unroll
    for (int i = 0; i < 4; ++i)
#pragma unroll
      for (int j = 0; j < 4; ++j)
#pragma unroll
        for (int r = 0; r < 4; ++r) {
          const int row = m0 + wr * 64 + i * 16 + rb + r;
          const int col = n0 + wc * 64 + j * 16 + cs;
          const float e = __expf(acc[i][j][r]);
          Cb[(size_t)bz * sC + (size_t)row * ldc + col] = (bf16_t)e;
          rsum[i][r] += e;
        }
#pragma unroll
    for (int off = 1; off < 16; off <<= 1)
#pragma unroll
      for (int i = 0; i < 4; ++i)
#pragma unroll
        for (int r = 0; r < 4; ++r)
          rsum[i][r] += __shfl_xor(rsum[i][r], off);
    if ((lane & 15) == 0) {
#pragma unroll
      for (int i = 0; i < 4; ++i)
#pragma unroll
        for (int r = 0; r < 4; ++r)
          atomicAdd(&Rsum[bz * 2048 + m0 + wr * 64 + i * 16 + rb + r],
                    rsum[i][r]);
    }
  } else {
    // fp32 out, normalized by 1/Rsum[row]
    float* Ob = (float*)C + (size_t)bz * sC;
#pragma unroll
    for (int i = 0; i < 4; ++i) {
#pragma unroll
      for (int r = 0; r < 4; ++r) {
        const int row = m0 + wr * 64 + i * 16 + rb + r;
        const float inv = 1.0f / Rsum[bz * 2048 + row];
#pragma unroll
        for (int j = 0; j < 4; ++j) {
          const int col = n0 + wc * 64 + j * 16 + cs;
          Ob[(size_t)row * ldc + col] = acc[i][j][r] * inv;
        }
      }
    }
  }
}

// ---------------------------------------------------------------------------
// launch
// ---------------------------------------------------------------------------
extern "C" void kernel_launch(void* const* d_in, const int* in_sizes, int n_in,
                              void* d_out, int out_size, void* d_ws,
                              size_t ws_size, hipStream_t stream) {
  const float* x = (const float*)d_in[0];  // [4,2048,1024]
  const float* W = (const float*)d_in[1];  // [1024,3072]
  const float* b = (const float*)d_in[2];  // [3072]
  float* out = (float*)d_out;              // [4,2048,1024] fp32

  char* w = (char*)d_ws;
  bf16_t* xb = (bf16_t*)w;   w += (size_t)8192 * 1024 * 2;
  bf16_t* Wt = (bf16_t*)w;   w += (size_t)3072 * 1024 * 2;
  bf16_t* QKV = (bf16_t*)w;  w += (size_t)2 * 8192 * 1024 * 2;  // Q,K dense
  bf16_t* Vt = (bf16_t*)w;   w += (size_t)4 * 1024 * 2048 * 2;
  bf16_t* E = (bf16_t*)w;    w += (size_t)4 * 2048 * 2048 * 2;  // exp(S)
  float* Rsum = (float*)w;   w += (size_t)8192 * 4;

  bf16_t* Q = QKV;
  bf16_t* Kd = QKV + (size_t)8192 * 1024;

  zero_f32<<<32, 256, 0, stream>>>(Rsum, 8192);
  cast_f32_bf16<<<8192, 256, 0, stream>>>(x, xb, (long)8192 * 1024);
  transpose_W<<<dim3(48, 16), 256, 0, stream>>>(W, Wt);

  // Q|K dense + V transposed into Vt. grid 24x64 = 1536 blocks, 16 phases
  gemm128<0, 16><<<dim3(24, 64, 1), 256, 0, stream>>>(
      xb, Wt, QKV, b, 1024, 1024, 1024, 0, 0, 0, Vt, nullptr);

  // E = exp(Qs @ K^T) bf16 + row sums. grid 16x16x4 = 1024 blocks, 16 phases
  gemm128<2, 16><<<dim3(16, 16, 4), 256, 0, stream>>>(
      Q, Kd, E, nullptr, 1024, 1024, 2048,
      (long)2048 * 1024, (long)2048 * 1024, (long)2048 * 2048,
      nullptr, Rsum);

  // out = (E @ Vt^T) / Rsum[row], fp32. grid 8x16x4 = 512 blocks, 32 phases
  gemm128<1, 32><<<dim3(8, 16, 4), 256, 0, stream>>>(
      E, Vt, out, nullptr, 2048, 2048, 1024,
      (long)2048 * 2048, (long)1024 * 2048, (long)2048 * 1024,
      nullptr, Rsum);
}